// Round 7
// baseline (1878.671 us; speedup 1.0000x reference)
//
#include <hip/hip_runtime.h>
#include <math.h>

// QLSTMHarmonic: persistent LSTM, 1 batch element/thread, 256 blk x 512 thr.
// Round-7 change (isolated): weights moved from LDS broadcast (ds_read_b128,
// ~205k DS instr/CU, DS-pipe-bound at 2 waves/SIMD) to a global quantized
// buffer read with thread-UNIFORM addresses -> compiler emits s_load through
// the scalar cache (6.4KB W_hh is K$-resident) and the matvec becomes
// v_fmac_f32 v,s,v with zero DS traffic. kprep quantizes weights once
// (same IEEE rintf(w/s) formula -> bit-exact unchanged, absmax 0.0 r3-r6).
// Barrier: RELAXED packed {tag,val} u64 slots (validated r6: ~4-5us/phase).
// ws layout (floats): [0] xmax bits | [8] sx | [64..1088) barrier slots
//                     [1088..6224) quantized weights (24.9KB)

#define NBLK  256
#define NTHR  512
#define SEQL  64
#define HIDN  20
#define G4    80     // 4*HID gates

// wq-relative float offsets
#define OF_WIH 0
#define OF_WHH 80      // [k*80+j], 1600
#define OF_W1  1680    // [k*64+j], 1280
#define OF_W2  2960    // [k*32+j], 2048
#define OF_W3  5008    // [k*4+j],  128
#define NQ     5136

// XLA/Eigen f32 tanh rational approximation (bit-exact vs reference, r3-r6).
__device__ __forceinline__ float tanh_xla(float x){
  const float kClamp = 7.90531110763549805f;
  float xc = fminf(fmaxf(x, -kClamp), kClamp);
  float x2 = xc*xc;
  float p = fmaf(x2, -2.76076847742355e-16f, 2.00018790482477e-13f);
  p = fmaf(x2, p, -8.60467152213735e-11f);
  p = fmaf(x2, p,  5.12229709037114e-08f);
  p = fmaf(x2, p,  1.48572235717979e-05f);
  p = fmaf(x2, p,  6.37261928875436e-04f);
  p = fmaf(x2, p,  4.89352455891786e-03f);
  p = p * xc;
  float q = fmaf(x2, 1.19825839466702e-06f, 1.18534705686654e-04f);
  q = fmaf(x2, q, 2.26843463243900e-03f);
  q = fmaf(x2, q, 4.89352518554385e-03f);
  float y = p / q;                       // IEEE div, as XLA emits
  return (fabsf(x) < 4e-4f) ? x : y;     // XLA small-x passthrough
}

// n = rintf(RN(x/s)) without a division in the common case (bit-exact r4-r6).
__device__ __forceinline__ float qround(float x, float s, float inv_s, float tol){
  float n = rintf(__fmul_rn(x, inv_s));
  float e = fmaf(-n, s, x);
  if (__builtin_expect(fabsf(fabsf(e) - 0.5f*s) <= tol*s, 0))
    n = rintf(x / s);
  return n;
}

// Combined global max-reduce + barrier (validated r6). RELAXED u64 atomics:
// slot = ((phase+1)<<32) | float_bits(block_max); 2 rows, row = phase&1.
__device__ __forceinline__ float phase_max(float lmax, int phase,
                                           unsigned long long* slots,
                                           int blk, int tid, float* s_red, float* s_bc)
{
  #pragma unroll
  for (int off=32; off; off>>=1) lmax = fmaxf(lmax, __shfl_xor(lmax, off, 64));
  int wid = tid>>6, lane = tid&63;
  if (lane==0) s_red[wid] = lmax;
  __syncthreads();
  if (wid==0) {
    float bm = s_red[lane&7];                    // 8 waves/block
    bm = fmaxf(bm, __shfl_xor(bm,4,64));
    bm = fmaxf(bm, __shfl_xor(bm,2,64));
    bm = fmaxf(bm, __shfl_xor(bm,1,64));
    unsigned long long* sp = slots + (size_t)(phase&1)*NBLK;
    const unsigned long long tagw = ((unsigned long long)(unsigned)(phase+1))<<32;
    if (lane==0)
      __hip_atomic_store(sp+blk, tagw | (unsigned long long)__float_as_uint(bm),
                         __ATOMIC_RELAXED, __HIP_MEMORY_SCOPE_AGENT);
    unsigned long long v0,v1,v2,v3;
    const unsigned int tag = (unsigned int)(phase+1);
    for (;;) {
      v0 = __hip_atomic_load(sp+lane,     __ATOMIC_RELAXED, __HIP_MEMORY_SCOPE_AGENT);
      v1 = __hip_atomic_load(sp+lane+64,  __ATOMIC_RELAXED, __HIP_MEMORY_SCOPE_AGENT);
      v2 = __hip_atomic_load(sp+lane+128, __ATOMIC_RELAXED, __HIP_MEMORY_SCOPE_AGENT);
      v3 = __hip_atomic_load(sp+lane+192, __ATOMIC_RELAXED, __HIP_MEMORY_SCOPE_AGENT);
      bool ok = ((unsigned)(v0>>32)==tag) && ((unsigned)(v1>>32)==tag) &&
                ((unsigned)(v2>>32)==tag) && ((unsigned)(v3>>32)==tag);
      if (__all(ok)) break;
      __builtin_amdgcn_s_sleep(1);
    }
    unsigned int m0 = (unsigned int)v0, m1 = (unsigned int)v1;
    unsigned int m2 = (unsigned int)v2, m3 = (unsigned int)v3;
    unsigned int m = m0>m1?m0:m1; if (m2>m) m=m2; if (m3>m) m=m3;
    #pragma unroll
    for (int off=32; off; off>>=1) {
      unsigned int o = (unsigned int)__shfl_xor((int)m, off, 64);
      if (o>m) m=o;
    }
    if (lane==0) *s_bc = __uint_as_float(m);   // non-negative: uint cmp == float cmp
  }
  __syncthreads();
  return *s_bc;
}

__global__ void kinit(float* __restrict__ ws) {
  int i = threadIdx.x;
  for (; i < 1088; i += 256) ws[i] = 0.0f;     // xmax + scales + 2x256 u64 slots
}

__global__ void kmaxabs_x(const float4* __restrict__ x4, int n4, int* __restrict__ xmax_bits) {
  float m = 0.f;
  int stride = gridDim.x*blockDim.x;
  for (int i = blockIdx.x*blockDim.x + threadIdx.x; i < n4; i += stride) {
    float4 v = x4[i];
    m = fmaxf(fmaxf(fabsf(v.x),fabsf(v.y)), fmaxf(fmaxf(fabsf(v.z),fabsf(v.w)), m));
  }
  #pragma unroll
  for (int off=32; off; off>>=1) m = fmaxf(m, __shfl_xor(m, off, 64));
  __shared__ float red[4];
  int wid = threadIdx.x>>6, lane = threadIdx.x&63;
  if (lane==0) red[wid]=m;
  __syncthreads();
  if (threadIdx.x==0) {
    float bm = fmaxf(fmaxf(red[0],red[1]), fmaxf(red[2],red[3]));
    atomicMax(xmax_bits, __float_as_int(bm));  // ws[0] zeroed by kinit; values >= 0
  }
}

// Scales + one-time weight fake-quantization into ws[1088..): exact same
// IEEE rintf(w/s) sequence as the former per-block LDS staging (bit-exact).
__global__ void kprep(const float* __restrict__ wih, const float* __restrict__ whh,
                      const float* __restrict__ W1, const float* __restrict__ W2,
                      const float* __restrict__ W3, float* __restrict__ ws)
{
  __shared__ float sc[6];
  int tid = threadIdx.x, wid = tid>>6, lane = tid&63;
  if (wid < 5) {
    const float* p; int n;
    if      (wid==0){p=wih;n=80;}   else if (wid==1){p=whh;n=1600;}
    else if (wid==2){p=W1;n=1280;}  else if (wid==3){p=W2;n=2048;}
    else            {p=W3;n=128;}
    float m=0.f;
    for (int i=lane;i<n;i+=64) m=fmaxf(m,fabsf(p[i]));
    #pragma unroll
    for (int off=32; off; off>>=1) m=fmaxf(m,__shfl_xor(m,off,64));
    if (lane==0) sc[1+wid]=fmaxf(m,1e-8f)/127.0f;
  }
  if (tid==0) {
    float xm = __int_as_float(((const int*)ws)[0]);
    float sx = fmaxf(xm,1e-8f)/127.0f;
    sc[0] = sx; ws[8] = sx;
  }
  __syncthreads();
  float* wq = ws + 1088;
  for (int i=tid; i<NQ; i+=512) {
    float s, v; int dst;
    if (i < 80)        { s=sc[1]; v=wih[i]; dst=OF_WIH + i; }
    else if (i < 1680) { int e=i-80;   int j=e/20, k=e-j*20; s=sc[2]; v=whh[e]; dst=OF_WHH + k*80 + j; }
    else if (i < 2960) { int e=i-1680; int j=e/20, k=e-j*20; s=sc[3]; v=W1[e];  dst=OF_W1  + k*64 + j; }
    else if (i < 5008) { int e=i-2960; int j=e>>6, k=e&63;   s=sc[4]; v=W2[e];  dst=OF_W2  + k*32 + j; }
    else               { int e=i-5008; int j=e>>5, k=e&31;   s=sc[5]; v=W3[e];  dst=OF_W3  + k*4  + j; }
    wq[dst] = fminf(fmaxf(rintf(v/s), -127.f), 127.f)*s;
  }
}

__global__ void __launch_bounds__(NTHR, 2)
kmain(const float* __restrict__ x, const float* __restrict__ bias,
      const float* __restrict__ b1, const float* __restrict__ b2,
      const float* __restrict__ b3, float* __restrict__ out,
      unsigned long long* __restrict__ slots,   // ws+64, 2*NBLK u64
      const float* __restrict__ wq,             // ws+1088, quantized weights
      const float* __restrict__ wsbase)         // ws, for sx at [8]
{
  __shared__ float s_lutsig[63];     // per-gate-phase: quantized sigmoid of n*s1
  __shared__ float s_luttg[63];      // per-gate-phase: quantized tanh of n*s1
  __shared__ float s_luttc[63];      // per-cell-phase: quantized tanh of m*s2
  __shared__ float s_red[8];
  __shared__ float s_bc;

  const int tid = threadIdx.x;
  const int blk = blockIdx.x;

  const float sx = wsbase[8];
  const float* wih = wq + OF_WIH;    // uniform scalar reads
  const float* whh = wq + OF_WHH;    // [k*80+j]

  const long bI = (long)blk*NTHR + tid;
  const float* xrow = x + bI*SEQL;
  const float inv_sx = __builtin_amdgcn_rcpf(sx);

  float h[HIDN], c[HIDN];
  #pragma unroll
  for (int k=0;k<HIDN;++k){ h[k]=0.f; c[k]=0.f; }

  float4 x4v;
  #pragma unroll 1
  for (int t=0; t<SEQL; ++t) {
    if ((t&3)==0) x4v = *(const float4*)(xrow + t);
    float xv = (t&3)==1 ? x4v.y : ((t&3)==2 ? x4v.z : ((t&3)==3 ? x4v.w : x4v.x));
    float xq = __fmul_rn(fminf(fmaxf(qround(xv, sx, inv_sx, 1e-4f), -127.f), 127.f), sx);

    // hw = h @ w_hh^T, k-ordered fma from 0 (canonical dot order).
    // whh[k*80+j]: thread-uniform address -> s_load + v_fmac v,s,v (no DS).
    float hw[G4];
    #pragma unroll
    for (int j=0;j<G4;++j) hw[j]=0.f;
    #pragma unroll
    for (int k=0;k<HIDN;++k) {
      float hk = h[k];
      #pragma unroll
      for (int j=0;j<G4;++j)
        hw[j] = fmaf(hk, whh[k*G4+j], hw[j]);
    }
    // gates = (x@wihT + hw) + b, left-assoc, no contraction
    float lm = 0.f;
    #pragma unroll
    for (int j=0;j<G4;++j) {
      float g = __fadd_rn(__fadd_rn(__fmul_rn(xq, wih[j]), hw[j]), bias[j]);
      hw[j] = g;
      lm = fmaxf(lm, fabsf(g));
    }
    float gm = phase_max(lm, 2*t, slots, blk, tid, s_red, &s_bc);
    float s1 = fmaxf(gm, 1e-8f)/31.0f;        // gate_acc scale (uniform)
    float inv1 = __builtin_amdgcn_rcpf(s1);

    // Activation LUTs for the 63 possible quantized-gate values (bit-exact:
    // identical instruction sequence on input RN(n*s1)).
    if (tid < 63) {
      float q  = __fmul_rn((float)(tid-31), s1);
      float ti = tanh_xla(0.5f*q);
      int ni = (int)rintf(fmaf(0.5f, ti, 0.5f)*63.0f);
      ni = min(max(ni,0),63);
      s_lutsig[tid] = (float)ni/63.0f;
    } else if (tid >= 64 && tid < 127) {
      int n = tid - 64 - 31;
      float q  = __fmul_rn((float)n, s1);
      float tg = tanh_xla(q);
      int ng = (int)rintf(tg*31.0f);
      ng = min(max(ng,-31),31);
      s_luttg[tid-64] = (float)ng/31.0f;
    }
    __syncthreads();

    float og[HIDN];
    float lm2 = 0.f;
    #pragma unroll
    for (int k=0;k<HIDN;++k) {
      int ii = min(max((int)qround(hw[k   ], s1, inv1, 2e-5f),-31),31)+31;
      int fi = min(max((int)qround(hw[20+k], s1, inv1, 2e-5f),-31),31)+31;
      int gi = min(max((int)qround(hw[40+k], s1, inv1, 2e-5f),-31),31)+31;
      int oi = min(max((int)qround(hw[60+k], s1, inv1, 2e-5f),-31),31)+31;
      float iv = s_lutsig[ii];
      float fv = s_lutsig[fi];
      float gv = s_luttg[gi];
      og[k]    = s_lutsig[oi];
      // c_new = (f*c) + (i*g), unfused
      float pc = __fadd_rn(__fmul_rn(fv, c[k]), __fmul_rn(iv, gv));
      c[k] = pc;
      lm2 = fmaxf(lm2, fabsf(pc));
    }
    float gm2 = phase_max(lm2, 2*t+1, slots, blk, tid, s_red, &s_bc);
    float s2 = fmaxf(gm2, 1e-8f)/31.0f;       // cell_state scale (uniform)
    float inv2 = __builtin_amdgcn_rcpf(s2);
    if (tid < 63) {
      float q  = __fmul_rn((float)(tid-31), s2);
      float tc = tanh_xla(q);
      int nc = (int)rintf(tc*31.0f);
      nc = min(max(nc,-31),31);
      s_luttc[tid] = (float)nc/31.0f;
    }
    __syncthreads();
    #pragma unroll
    for (int k=0;k<HIDN;++k) {
      int m = min(max((int)qround(c[k], s2, inv2, 2e-5f),-31),31);
      float cn = __fmul_rn((float)m, s2);
      c[k] = cn;
      h[k] = __fmul_rn(og[k], s_luttc[m+31]);
    }
  }

  // ---- MLP head (weights via uniform scalar reads) ----
  const float* W1q = wq + OF_W1;     // [k*64+j]
  const float* W2q = wq + OF_W2;     // [k*32+j]
  const float* W3q = wq + OF_W3;     // [k*4+j]

  float lm3 = 0.f;
  float a0[HIDN];
  #pragma unroll
  for (int k=0;k<HIDN;++k){ float r = fmaxf(h[k],0.f); a0[k]=r; lm3=fmaxf(lm3,r); }
  float gm3 = phase_max(lm3, 128, slots, blk, tid, s_red, &s_bc);
  float s3 = fmaxf(gm3,1e-8f)/63.0f;          // unsigned 6b
  float inv3 = __builtin_amdgcn_rcpf(s3);
  #pragma unroll
  for (int k=0;k<HIDN;++k)
    a0[k] = __fmul_rn(fminf(fmaxf(qround(a0[k], s3, inv3, 4e-5f),0.f),63.f), s3);

  float o1[64];
  #pragma unroll
  for (int j=0;j<64;++j) o1[j] = 0.f;
  #pragma unroll
  for (int k=0;k<HIDN;++k) {
    float ak = a0[k];
    #pragma unroll
    for (int j=0;j<64;++j) o1[j] = fmaf(ak, W1q[k*64+j], o1[j]);
  }
  float lm4 = 0.f;
  #pragma unroll
  for (int j=0;j<64;++j){ o1[j]=fmaxf(__fadd_rn(o1[j],b1[j]),0.f); lm4=fmaxf(lm4,o1[j]); }
  float gm4 = phase_max(lm4, 129, slots, blk, tid, s_red, &s_bc);
  float s4 = fmaxf(gm4,1e-8f)/63.0f;
  float inv4 = __builtin_amdgcn_rcpf(s4);
  #pragma unroll
  for (int j=0;j<64;++j)
    o1[j] = __fmul_rn(fminf(fmaxf(qround(o1[j], s4, inv4, 4e-5f),0.f),63.f), s4);

  float o2[32];
  #pragma unroll
  for (int j=0;j<32;++j) o2[j] = 0.f;
  #pragma unroll
  for (int k=0;k<64;++k) {
    float ak = o1[k];
    #pragma unroll
    for (int j=0;j<32;++j) o2[j] = fmaf(ak, W2q[k*32+j], o2[j]);
  }
  float lm5=0.f;
  #pragma unroll
  for (int j=0;j<32;++j){ o2[j]=fmaxf(__fadd_rn(o2[j],b2[j]),0.f); lm5=fmaxf(lm5,o2[j]); }
  float gm5 = phase_max(lm5, 130, slots, blk, tid, s_red, &s_bc);
  float s5 = fmaxf(gm5,1e-8f)/63.0f;
  float inv5 = __builtin_amdgcn_rcpf(s5);
  #pragma unroll
  for (int j=0;j<32;++j)
    o2[j] = __fmul_rn(fminf(fmaxf(qround(o2[j], s5, inv5, 4e-5f),0.f),63.f), s5);

  float o3[4] = {0.f,0.f,0.f,0.f};
  #pragma unroll
  for (int k=0;k<32;++k) {
    float ak = o2[k];
    #pragma unroll
    for (int j=0;j<4;++j) o3[j] = fmaf(ak, W3q[k*4+j], o3[j]);
  }
  float4 res;
  res.x = fmaxf(__fadd_rn(o3[0],b3[0]),0.f);
  res.y = fmaxf(__fadd_rn(o3[1],b3[1]),0.f);
  res.z = fmaxf(__fadd_rn(o3[2],b3[2]),0.f);
  res.w = fmaxf(__fadd_rn(o3[3],b3[3]),0.f);
  ((float4*)out)[bI] = res;
}

extern "C" void kernel_launch(void* const* d_in, const int* in_sizes, int n_in,
                              void* d_out, int out_size, void* d_ws, size_t ws_size,
                              hipStream_t stream) {
  const float* x    = (const float*)d_in[0];
  const float* w_ih = (const float*)d_in[1];
  const float* w_hh = (const float*)d_in[2];
  const float* b    = (const float*)d_in[3];
  const float* W1   = (const float*)d_in[4];
  const float* b1   = (const float*)d_in[5];
  const float* W2   = (const float*)d_in[6];
  const float* b2   = (const float*)d_in[7];
  const float* W3   = (const float*)d_in[8];
  const float* b3   = (const float*)d_in[9];
  float* out = (float*)d_out;
  float* ws  = (float*)d_ws;

  int n4 = in_sizes[0]/4;
  kinit<<<1,256,0,stream>>>(ws);
  kmaxabs_x<<<1024,256,0,stream>>>((const float4*)x, n4, (int*)ws);
  kprep<<<1,512,0,stream>>>(w_ih,w_hh,W1,W2,W3,ws);
  // Plain launch (NOT cooperative: not graph-capturable). Co-residency is
  // structural: 256 blocks, 1 block/CU x 256 CUs at __launch_bounds__(512,2).
  kmain<<<dim3(NBLK), dim3(NTHR), 0, stream>>>(
      x, b, b1, b2, b3, out,
      (unsigned long long*)(ws + 64), ws + 1088, ws);
}

// Round 8
// 1325.592 us; speedup vs baseline: 1.4172x; 1.4172x over previous
//
#include <hip/hip_runtime.h>
#include <math.h>

// QLSTMHarmonic: persistent LSTM, 1 batch element/thread, 256 blk x 512 thr.
// r8 = r6 base (LDS weights, relaxed u64 slot barrier; 1327us, absmax 0.0)
//  + packed fp32 matvec (v_pk_fma_f32 via float2, bit-exact: IEEE fma/half,
//    same k-order accumulation)
//  + sync-free barrier: tagged LDS words (ds b64) replace both __syncthreads
//    in phase_max; global slot protocol unchanged.
// r7 lesson: weights in the ws global buffer -> per-step EA re-fetch (+135MB,
// +500us). Weights stay in LDS.

#define NBLK  256
#define NTHR  512
#define SEQL  64
#define HIDN  20
#define G4    80     // 4*HID gates

typedef float f2 __attribute__((ext_vector_type(2)));
typedef unsigned long long u64;

// XLA/Eigen f32 tanh rational approximation (bit-exact vs reference, r3-r6).
__device__ __forceinline__ float tanh_xla(float x){
  const float kClamp = 7.90531110763549805f;
  float xc = fminf(fmaxf(x, -kClamp), kClamp);
  float x2 = xc*xc;
  float p = fmaf(x2, -2.76076847742355e-16f, 2.00018790482477e-13f);
  p = fmaf(x2, p, -8.60467152213735e-11f);
  p = fmaf(x2, p,  5.12229709037114e-08f);
  p = fmaf(x2, p,  1.48572235717979e-05f);
  p = fmaf(x2, p,  6.37261928875436e-04f);
  p = fmaf(x2, p,  4.89352455891786e-03f);
  p = p * xc;
  float q = fmaf(x2, 1.19825839466702e-06f, 1.18534705686654e-04f);
  q = fmaf(x2, q, 2.26843463243900e-03f);
  q = fmaf(x2, q, 4.89352518554385e-03f);
  float y = p / q;                       // IEEE div, as XLA emits
  return (fabsf(x) < 4e-4f) ? x : y;     // XLA small-x passthrough
}

// n = rintf(RN(x/s)) without a division in the common case (bit-exact r4-r6).
__device__ __forceinline__ float qround(float x, float s, float inv_s, float tol){
  float n = rintf(__fmul_rn(x, inv_s));
  float e = fmaf(-n, s, x);
  if (__builtin_expect(fabsf(fabsf(e) - 0.5f*s) <= tol*s, 0))
    n = rintf(x / s);
  return n;
}

// Combined global max-reduce + barrier, zero __syncthreads.
// In-block: tagged LDS words (ds b64 single-op). Cross-block: r6's relaxed
// u64 {tag,val} slots, 2 rows, row=phase&1, tag=phase+1 (monotonic; stale
// row tag p-1 != p+1 -> no false positive). Only wave0 polls global slots.
// Causality: every wave's next-phase LDS writes happen after it passed this
// phase's bcast spin, which is after wave0 consumed s_red64 -> no overwrite
// race; row p+2 publish is gated through two poll generations -> no ABA.
__device__ __forceinline__ float phase_max(float lmax, int phase,
                                           u64* slots, int blk, int tid,
                                           volatile u64* s_red64,
                                           volatile u64* s_bc64)
{
  #pragma unroll
  for (int off=32; off; off>>=1) lmax = fmaxf(lmax, __shfl_xor(lmax, off, 64));
  const int wid = tid>>6, lane = tid&63;
  const unsigned int tag = (unsigned int)(phase+1);
  const u64 tw = ((u64)tag)<<32;
  if (lane==0) s_red64[wid] = tw | (u64)__float_as_uint(lmax);
  if (wid==0) {
    // gather the 8 per-wave partials by tag-spin (lanes 0..7)
    u64 pv = 0;
    if (lane<8) { do { pv = s_red64[lane]; } while ((unsigned int)(pv>>32)!=tag); }
    float bm = (lane<8) ? __uint_as_float((unsigned int)pv) : 0.f;
    bm = fmaxf(bm, __shfl_xor(bm,4,64));
    bm = fmaxf(bm, __shfl_xor(bm,2,64));
    bm = fmaxf(bm, __shfl_xor(bm,1,64));
    u64* sp = slots + (size_t)(phase&1)*NBLK;
    if (lane==0)
      __hip_atomic_store(sp+blk, tw | (u64)__float_as_uint(bm),
                         __ATOMIC_RELAXED, __HIP_MEMORY_SCOPE_AGENT);
    u64 v0,v1,v2,v3;
    for (;;) {
      v0 = __hip_atomic_load(sp+lane,     __ATOMIC_RELAXED, __HIP_MEMORY_SCOPE_AGENT);
      v1 = __hip_atomic_load(sp+lane+64,  __ATOMIC_RELAXED, __HIP_MEMORY_SCOPE_AGENT);
      v2 = __hip_atomic_load(sp+lane+128, __ATOMIC_RELAXED, __HIP_MEMORY_SCOPE_AGENT);
      v3 = __hip_atomic_load(sp+lane+192, __ATOMIC_RELAXED, __HIP_MEMORY_SCOPE_AGENT);
      bool ok = ((unsigned int)(v0>>32)==tag) && ((unsigned int)(v1>>32)==tag) &&
                ((unsigned int)(v2>>32)==tag) && ((unsigned int)(v3>>32)==tag);
      if (__all(ok)) break;
      __builtin_amdgcn_s_sleep(1);
    }
    unsigned int m0 = (unsigned int)v0, m1 = (unsigned int)v1;
    unsigned int m2 = (unsigned int)v2, m3 = (unsigned int)v3;
    unsigned int m = m0>m1?m0:m1; if (m2>m) m=m2; if (m3>m) m=m3;
    #pragma unroll
    for (int off=32; off; off>>=1) {
      unsigned int o = (unsigned int)__shfl_xor((int)m, off, 64);
      if (o>m) m=o;
    }
    if (lane==0) *s_bc64 = tw | (u64)m;      // non-neg floats: uint cmp == float cmp
  }
  u64 bv;
  do { bv = *s_bc64; } while ((unsigned int)(bv>>32)!=tag);
  return __uint_as_float((unsigned int)bv);
}

__global__ void kinit(float* __restrict__ ws) {
  int i = threadIdx.x;
  for (; i < 1152; i += 256) ws[i] = 0.0f;     // xmax + scales + 2x256 u64 slots
}

__global__ void kmaxabs_x(const float4* __restrict__ x4, int n4, int* __restrict__ xmax_bits) {
  float m = 0.f;
  int stride = gridDim.x*blockDim.x;
  for (int i = blockIdx.x*blockDim.x + threadIdx.x; i < n4; i += stride) {
    float4 v = x4[i];
    m = fmaxf(fmaxf(fabsf(v.x),fabsf(v.y)), fmaxf(fmaxf(fabsf(v.z),fabsf(v.w)), m));
  }
  #pragma unroll
  for (int off=32; off; off>>=1) m = fmaxf(m, __shfl_xor(m, off, 64));
  __shared__ float red[4];
  int wid = threadIdx.x>>6, lane = threadIdx.x&63;
  if (lane==0) red[wid]=m;
  __syncthreads();
  if (threadIdx.x==0) {
    float bm = fmaxf(fmaxf(red[0],red[1]), fmaxf(red[2],red[3]));
    atomicMax(xmax_bits, __float_as_int(bm));  // ws[0] zeroed by kinit; values >= 0
  }
}

__global__ void kscales(const float* __restrict__ wih, const float* __restrict__ whh,
                        const float* __restrict__ W1, const float* __restrict__ W2,
                        const float* __restrict__ W3, float* __restrict__ ws)
{
  int wid = threadIdx.x>>6, lane = threadIdx.x&63;
  const float* p; int n;
  if      (wid==0){p=wih;n=80;}   else if (wid==1){p=whh;n=1600;}
  else if (wid==2){p=W1;n=1280;}  else if (wid==3){p=W2;n=2048;}
  else            {p=W3;n=128;}
  float m=0.f;
  for (int i=lane;i<n;i+=64) m=fmaxf(m,fabsf(p[i]));
  #pragma unroll
  for (int off=32; off; off>>=1) m=fmaxf(m,__shfl_xor(m,off,64));
  if (lane==0) ws[9+wid]=fmaxf(m,1e-8f)/127.0f;
  if (threadIdx.x==0) {
    float xm = __int_as_float(((const int*)ws)[0]);
    ws[8]=fmaxf(xm,1e-8f)/127.0f;
  }
}

__global__ void __launch_bounds__(NTHR, 2)
kmain(const float* __restrict__ x, const float* __restrict__ w_ih,
      const float* __restrict__ w_hh, const float* __restrict__ bias,
      const float* __restrict__ W1, const float* __restrict__ b1,
      const float* __restrict__ W2, const float* __restrict__ b2,
      const float* __restrict__ W3, const float* __restrict__ b3,
      float* __restrict__ out, float* __restrict__ ws)
{
  __shared__ float s_whh[HIDN*G4];   // [k][j]
  __shared__ float s_wih[G4];
  __shared__ float s_b[G4];
  __shared__ float s_W1[HIDN*64];    // [k][j]
  __shared__ float s_b1v[64];
  __shared__ float s_W2[64*32];      // [k][j]
  __shared__ float s_b2v[32];
  __shared__ float s_W3[32*4];       // [k][j]
  __shared__ float s_b3v[4];
  __shared__ float s_lutsig[63];     // per-gate-phase: quantized sigmoid of n*s1
  __shared__ float s_luttg[63];      // per-gate-phase: quantized tanh of n*s1
  __shared__ float s_luttc[63];      // per-cell-phase: quantized tanh of m*s2
  __shared__ u64 s_red64[8];
  __shared__ u64 s_bc64;

  const int tid = threadIdx.x;
  const int blk = blockIdx.x;
  u64* slots = (u64*)(ws + 64);      // 2*NBLK u64

  const float sx   = ws[8];
  const float swih = ws[9];
  const float swhh = ws[10];
  const float sw1  = ws[11];
  const float sw2  = ws[12];
  const float sw3  = ws[13];

  // stage + fake-quantize weights into LDS ([k][j] layout, float4 j-reads).
  // One-time cost: IEEE div keeps this bit-exact vs reference.
  for (int i = tid; i < G4; i += NTHR) {
    s_wih[i] = fminf(fmaxf(rintf(w_ih[i]/swih), -127.f), 127.f)*swih;
    s_b[i]   = bias[i];
  }
  for (int i = tid; i < HIDN*G4; i += NTHR) {
    int j = i/HIDN, k = i - j*HIDN;           // src w_hh[j][k]
    s_whh[k*G4+j] = fminf(fmaxf(rintf(w_hh[i]/swhh), -127.f), 127.f)*swhh;
  }
  for (int i = tid; i < 64*HIDN; i += NTHR) {
    int j = i/HIDN, k = i - j*HIDN;           // src W1[j][k]
    s_W1[k*64+j] = fminf(fmaxf(rintf(W1[i]/sw1), -127.f), 127.f)*sw1;
  }
  for (int i = tid; i < 32*64; i += NTHR) {
    int j = i>>6, k = i&63;                   // src W2[j][k]
    s_W2[k*32+j] = fminf(fmaxf(rintf(W2[i]/sw2), -127.f), 127.f)*sw2;
  }
  for (int i = tid; i < 4*32; i += NTHR) {
    int j = i>>5, k = i&31;                   // src W3[j][k]
    s_W3[k*4+j] = fminf(fmaxf(rintf(W3[i]/sw3), -127.f), 127.f)*sw3;
  }
  if (tid < 64) s_b1v[tid] = b1[tid];
  if (tid < 32) s_b2v[tid] = b2[tid];
  if (tid < 4)  s_b3v[tid] = b3[tid];
  __syncthreads();

  const long bI = (long)blk*NTHR + tid;
  const float* xrow = x + bI*SEQL;
  const float inv_sx = __builtin_amdgcn_rcpf(sx);

  float h[HIDN], c[HIDN];
  #pragma unroll
  for (int k=0;k<HIDN;++k){ h[k]=0.f; c[k]=0.f; }

  float4 x4v;
  #pragma unroll 1
  for (int t=0; t<SEQL; ++t) {
    if ((t&3)==0) x4v = *(const float4*)(xrow + t);
    float xv = (t&3)==1 ? x4v.y : ((t&3)==2 ? x4v.z : ((t&3)==3 ? x4v.w : x4v.x));
    float xq = __fmul_rn(fminf(fmaxf(qround(xv, sx, inv_sx, 1e-4f), -127.f), 127.f), sx);

    // hw = h @ w_hh^T, k-ordered fma from 0 (canonical dot order).
    // Packed: 2 gates per v_pk_fma_f32; identical per-element IEEE fma and
    // identical k-accumulation order -> bit-exact vs scalar version.
    f2 hw2[40];
    #pragma unroll
    for (int j=0;j<40;++j) { hw2[j].x = 0.f; hw2[j].y = 0.f; }
    #pragma unroll
    for (int k=0;k<HIDN;++k) {
      float hk = h[k];
      f2 hk2; hk2.x = hk; hk2.y = hk;
      const float4* w4 = (const float4*)&s_whh[k*G4];
      #pragma unroll
      for (int j4=0;j4<20;++j4) {
        float4 w = w4[j4];
        f2 wlo; wlo.x = w.x; wlo.y = w.y;
        f2 whi; whi.x = w.z; whi.y = w.w;
        hw2[2*j4]   = __builtin_elementwise_fma(hk2, wlo, hw2[2*j4]);
        hw2[2*j4+1] = __builtin_elementwise_fma(hk2, whi, hw2[2*j4+1]);
      }
    }
    float* hw = (float*)hw2;
    // gates = (x@wihT + hw) + b, left-assoc, no contraction (scalar _rn ops)
    float lm = 0.f;
    #pragma unroll
    for (int j4=0;j4<20;++j4) {
      float4 wi = *(const float4*)&s_wih[j4*4];
      float4 bb = *(const float4*)&s_b[j4*4];
      float g0 = __fadd_rn(__fadd_rn(__fmul_rn(xq, wi.x), hw[j4*4  ]), bb.x);
      float g1 = __fadd_rn(__fadd_rn(__fmul_rn(xq, wi.y), hw[j4*4+1]), bb.y);
      float g2 = __fadd_rn(__fadd_rn(__fmul_rn(xq, wi.z), hw[j4*4+2]), bb.z);
      float g3 = __fadd_rn(__fadd_rn(__fmul_rn(xq, wi.w), hw[j4*4+3]), bb.w);
      hw[j4*4  ]=g0; hw[j4*4+1]=g1; hw[j4*4+2]=g2; hw[j4*4+3]=g3;
      lm = fmaxf(lm, fmaxf(fmaxf(fabsf(g0),fabsf(g1)), fmaxf(fabsf(g2),fabsf(g3))));
    }
    float gm = phase_max(lm, 2*t, slots, blk, tid, s_red64, &s_bc64);
    float s1 = fmaxf(gm, 1e-8f)/31.0f;        // gate_acc scale (uniform)
    float inv1 = __builtin_amdgcn_rcpf(s1);

    // Activation LUTs for the 63 possible quantized-gate values (bit-exact:
    // identical instruction sequence on input RN(n*s1)).
    if (tid < 63) {
      float q  = __fmul_rn((float)(tid-31), s1);
      float ti = tanh_xla(0.5f*q);
      int ni = (int)rintf(fmaf(0.5f, ti, 0.5f)*63.0f);
      ni = min(max(ni,0),63);
      s_lutsig[tid] = (float)ni/63.0f;
    } else if (tid >= 64 && tid < 127) {
      int n = tid - 64 - 31;
      float q  = __fmul_rn((float)n, s1);
      float tg = tanh_xla(q);
      int ng = (int)rintf(tg*31.0f);
      ng = min(max(ng,-31),31);
      s_luttg[tid-64] = (float)ng/31.0f;
    }
    __syncthreads();

    float og[HIDN];
    float lm2 = 0.f;
    #pragma unroll
    for (int k=0;k<HIDN;++k) {
      int ii = min(max((int)qround(hw[k   ], s1, inv1, 2e-5f),-31),31)+31;
      int fi = min(max((int)qround(hw[20+k], s1, inv1, 2e-5f),-31),31)+31;
      int gi = min(max((int)qround(hw[40+k], s1, inv1, 2e-5f),-31),31)+31;
      int oi = min(max((int)qround(hw[60+k], s1, inv1, 2e-5f),-31),31)+31;
      float iv = s_lutsig[ii];
      float fv = s_lutsig[fi];
      float gv = s_luttg[gi];
      og[k]    = s_lutsig[oi];
      // c_new = (f*c) + (i*g), unfused
      float pc = __fadd_rn(__fmul_rn(fv, c[k]), __fmul_rn(iv, gv));
      c[k] = pc;
      lm2 = fmaxf(lm2, fabsf(pc));
    }
    float gm2 = phase_max(lm2, 2*t+1, slots, blk, tid, s_red64, &s_bc64);
    float s2 = fmaxf(gm2, 1e-8f)/31.0f;       // cell_state scale (uniform)
    float inv2 = __builtin_amdgcn_rcpf(s2);
    if (tid < 63) {
      float q  = __fmul_rn((float)(tid-31), s2);
      float tc = tanh_xla(q);
      int nc = (int)rintf(tc*31.0f);
      nc = min(max(nc,-31),31);
      s_luttc[tid] = (float)nc/31.0f;
    }
    __syncthreads();
    #pragma unroll
    for (int k=0;k<HIDN;++k) {
      int m = min(max((int)qround(c[k], s2, inv2, 2e-5f),-31),31);
      float cn = __fmul_rn((float)m, s2);
      c[k] = cn;
      h[k] = __fmul_rn(og[k], s_luttc[m+31]);
    }
  }

  // ---- MLP head (runs once; scalar form, LDS float4 weights) ----
  float lm3 = 0.f;
  float a0[HIDN];
  #pragma unroll
  for (int k=0;k<HIDN;++k){ float r = fmaxf(h[k],0.f); a0[k]=r; lm3=fmaxf(lm3,r); }
  float gm3 = phase_max(lm3, 128, slots, blk, tid, s_red64, &s_bc64);
  float s3 = fmaxf(gm3,1e-8f)/63.0f;          // unsigned 6b
  float inv3 = __builtin_amdgcn_rcpf(s3);
  #pragma unroll
  for (int k=0;k<HIDN;++k)
    a0[k] = __fmul_rn(fminf(fmaxf(qround(a0[k], s3, inv3, 4e-5f),0.f),63.f), s3);

  float o1[64];
  #pragma unroll
  for (int j=0;j<64;++j) o1[j] = 0.f;
  #pragma unroll
  for (int k=0;k<HIDN;++k) {
    float ak = a0[k];
    #pragma unroll
    for (int j=0;j<64;j+=4) {
      float4 w = *(const float4*)&s_W1[k*64+j];
      o1[j]   = fmaf(ak,w.x,o1[j]);
      o1[j+1] = fmaf(ak,w.y,o1[j+1]);
      o1[j+2] = fmaf(ak,w.z,o1[j+2]);
      o1[j+3] = fmaf(ak,w.w,o1[j+3]);
    }
  }
  float lm4 = 0.f;
  #pragma unroll
  for (int j=0;j<64;++j){ o1[j]=fmaxf(__fadd_rn(o1[j],s_b1v[j]),0.f); lm4=fmaxf(lm4,o1[j]); }
  float gm4 = phase_max(lm4, 129, slots, blk, tid, s_red64, &s_bc64);
  float s4 = fmaxf(gm4,1e-8f)/63.0f;
  float inv4 = __builtin_amdgcn_rcpf(s4);
  #pragma unroll
  for (int j=0;j<64;++j)
    o1[j] = __fmul_rn(fminf(fmaxf(qround(o1[j], s4, inv4, 4e-5f),0.f),63.f), s4);

  float o2[32];
  #pragma unroll
  for (int j=0;j<32;++j) o2[j] = 0.f;
  #pragma unroll
  for (int k=0;k<64;++k) {
    float ak = o1[k];
    #pragma unroll
    for (int j=0;j<32;j+=4) {
      float4 w = *(const float4*)&s_W2[k*32+j];
      o2[j]   = fmaf(ak,w.x,o2[j]);
      o2[j+1] = fmaf(ak,w.y,o2[j+1]);
      o2[j+2] = fmaf(ak,w.z,o2[j+2]);
      o2[j+3] = fmaf(ak,w.w,o2[j+3]);
    }
  }
  float lm5=0.f;
  #pragma unroll
  for (int j=0;j<32;++j){ o2[j]=fmaxf(__fadd_rn(o2[j],s_b2v[j]),0.f); lm5=fmaxf(lm5,o2[j]); }
  float gm5 = phase_max(lm5, 130, slots, blk, tid, s_red64, &s_bc64);
  float s5 = fmaxf(gm5,1e-8f)/63.0f;
  float inv5 = __builtin_amdgcn_rcpf(s5);
  #pragma unroll
  for (int j=0;j<32;++j)
    o2[j] = __fmul_rn(fminf(fmaxf(qround(o2[j], s5, inv5, 4e-5f),0.f),63.f), s5);

  float o3[4] = {0.f,0.f,0.f,0.f};
  #pragma unroll
  for (int k=0;k<32;++k) {
    float ak = o2[k];
    float4 w = *(const float4*)&s_W3[k*4];
    o3[0]=fmaf(ak,w.x,o3[0]); o3[1]=fmaf(ak,w.y,o3[1]);
    o3[2]=fmaf(ak,w.z,o3[2]); o3[3]=fmaf(ak,w.w,o3[3]);
  }
  float4 res;
  res.x = fmaxf(__fadd_rn(o3[0],s_b3v[0]),0.f);
  res.y = fmaxf(__fadd_rn(o3[1],s_b3v[1]),0.f);
  res.z = fmaxf(__fadd_rn(o3[2],s_b3v[2]),0.f);
  res.w = fmaxf(__fadd_rn(o3[3],s_b3v[3]),0.f);
  ((float4*)out)[bI] = res;
}

extern "C" void kernel_launch(void* const* d_in, const int* in_sizes, int n_in,
                              void* d_out, int out_size, void* d_ws, size_t ws_size,
                              hipStream_t stream) {
  const float* x    = (const float*)d_in[0];
  const float* w_ih = (const float*)d_in[1];
  const float* w_hh = (const float*)d_in[2];
  const float* b    = (const float*)d_in[3];
  const float* W1   = (const float*)d_in[4];
  const float* b1   = (const float*)d_in[5];
  const float* W2   = (const float*)d_in[6];
  const float* b2   = (const float*)d_in[7];
  const float* W3   = (const float*)d_in[8];
  const float* b3   = (const float*)d_in[9];
  float* out = (float*)d_out;
  float* ws  = (float*)d_ws;

  int n4 = in_sizes[0]/4;
  kinit<<<1,256,0,stream>>>(ws);
  kmaxabs_x<<<1024,256,0,stream>>>((const float4*)x, n4, (int*)ws);
  kscales<<<1,320,0,stream>>>(w_ih,w_hh,W1,W2,W3,ws);
  // Plain launch (NOT cooperative: not graph-capturable). Co-residency is
  // structural: 256 blocks, 1 block/CU x 256 CUs at __launch_bounds__(512,2).
  kmain<<<dim3(NBLK), dim3(NTHR), 0, stream>>>(x,w_ih,w_hh,b,W1,b1,W2,b2,W3,b3,out,ws);
}